// Round 13
// baseline (10.236 us; speedup 1.0000x reference)
//
#include <hip/hip_runtime.h>
#include <hip/hip_bf16.h>

#define D_Z 64
#define D_TOTAL 16448
#define NY 16384
#define TJ 32
#define N_YB (NY / TJ)   // 512
#define N_ZB 8
#define OPAD 33          // f32 out-stage row stride (pad -> ~2-way banks, free)

typedef __attribute__((ext_vector_type(8))) short bf16x8;
typedef __attribute__((ext_vector_type(4))) float f32x4;

__device__ __forceinline__ short f2bf(float x) {
    union { __hip_bfloat16 h; short s; } u;
    u.h = __float2bfloat16(x);   // RNE; pairs into v_cvt_pk_bf16_f32
    return u.s;
}

__device__ __forceinline__ bf16x8 packbf(float4 a, float4 b) {
    bf16x8 r = { f2bf(a.x), f2bf(a.y), f2bf(a.z), f2bf(a.w),
                 f2bf(b.x), f2bf(b.y), f2bf(b.z), f2bf(b.w) };
    return r;
}

// R11 structure + epilogue LDS-transpose so every out-store instruction
// writes full 128 B lines (8 lines/instr vs 16 scattered half-lines).
// Grid: blocks 0..7 -> z-part; blocks 8..519 -> y-part (32 cols x 128 samples).
__global__ __launch_bounds__(256, 2) void sv_kernel(
    const float* __restrict__ m,
    const float* __restrict__ Lz,     // tril(64), row-major tril order
    const float* __restrict__ Ly,     // N * 36, per-block tril(8)
    const float* __restrict__ Lyz,    // [NY x 64] row-major
    const float* __restrict__ eps,    // [128, 16448]
    float* __restrict__ out)          // [128, 16448]
{
    // one arena, carved: zs 16 KB | ys 8 KB | ls 4 KB  (28 KB)
    // epilogue reuses zs+ys (24 KB) as a 128 x OPAD f32 tile (16.9 KB)
    __shared__ __align__(16) char smem[28 * 1024];
    char* zsb = smem;
    char* ysb = smem + 16 * 1024;
    char* lsb = smem + 24 * 1024;

    const int tid = threadIdx.x;
    const int bb  = blockIdx.x;

    if (bb >= N_ZB) {
        // ================= y-part =================
        const int j0 = (bb - N_ZB) * TJ;

        const int r0z = tid >> 3;          // 0..31
        const int c8z = (tid & 7) << 3;    // 0..56
        const int r0y = tid >> 2;          // 0..63
        const int c8y = (tid & 3) << 3;    // 0,8,16,24

        // ---- PHASE 1: issue ALL staging loads into registers ----
        float4 rz[4][2], rl[2], ry[2][2];
        #pragma unroll
        for (int it = 0; it < 4; ++it) {
            const float* p = eps + (size_t)(r0z + (it << 5)) * D_TOTAL + c8z;
            rz[it][0] = *(const float4*)p;
            rz[it][1] = *(const float4*)(p + 4);
        }
        {
            const float* q = Lyz + (size_t)(j0 + r0z) * D_Z + c8z;
            rl[0] = *(const float4*)q;
            rl[1] = *(const float4*)(q + 4);
        }
        #pragma unroll
        for (int it = 0; it < 2; ++it) {
            const float* p = eps + (size_t)(r0y + (it << 6)) * D_TOTAL + D_Z + j0 + c8y;
            ry[it][0] = *(const float4*)p;
            ry[it][1] = *(const float4*)(p + 4);
        }

        // ---- independent per-lane loads (overlap with staging latency) ----
        const int w    = tid >> 6;
        const int lane = tid & 63;
        const int ln15 = lane & 15;
        const int lg   = lane >> 4;

        float  mj_[2];
        bf16x8 by_[2];
        #pragma unroll
        for (int st = 0; st < 2; ++st) {
            const int jy = j0 + (st << 4) + ln15;
            mj_[st] = m[D_Z + jy];
            const int r = ln15 & 7;
            const float* lyp = Ly + (size_t)(jy >> 3) * 36 + r * (r + 1) / 2;
            bf16x8 by = {0, 0, 0, 0, 0, 0, 0, 0};
            if (lg == (ln15 >> 3)) {
                float lyr[8];
                #pragma unroll
                for (int c = 0; c < 8; ++c) lyr[c] = (c <= r) ? lyp[c] : 0.0f;
                by = packbf(make_float4(lyr[0], lyr[1], lyr[2], lyr[3]),
                            make_float4(lyr[4], lyr[5], lyr[6], lyr[7]));
            }
            by_[st] = by;
        }

        // ---- PHASE 2: cvt + ds_write all staged tiles ----
        #pragma unroll
        for (int it = 0; it < 4; ++it) {
            const int row = r0z + (it << 5);
            *(bf16x8*)(zsb + row * 128 + ((c8z << 1) ^ ((row & 7) << 4))) =
                packbf(rz[it][0], rz[it][1]);
        }
        *(bf16x8*)(lsb + r0z * 128 + ((c8z << 1) ^ ((r0z & 7) << 4))) =
            packbf(rl[0], rl[1]);
        #pragma unroll
        for (int it = 0; it < 2; ++it) {
            const int row = r0y + (it << 6);
            *(bf16x8*)(ysb + row * 64 + ((c8y << 1) ^ ((row & 3) << 4))) =
                packbf(ry[it][0], ry[it][1]);
        }
        __syncthreads();

        // ---- A-z fragments (regs, reused across both subtiles) ----
        bf16x8 az[2][2];
        #pragma unroll
        for (int mt = 0; mt < 2; ++mt) {
            const int row = (w << 5) + (mt << 4) + ln15;
            #pragma unroll
            for (int ks = 0; ks < 2; ++ks) {
                az[mt][ks] = *(const bf16x8*)(zsb + row * 128 +
                                (((ks << 6) + (lg << 4)) ^ ((row & 7) << 4)));
            }
        }

        // ---- MFMA: all 16 outputs into registers ----
        float vout[2][2][4];   // [st][mt][reg]
        #pragma unroll
        for (int st = 0; st < 2; ++st) {
            bf16x8 bz[2];
            #pragma unroll
            for (int ks = 0; ks < 2; ++ks) {
                const int brow = (st << 4) + ln15;
                bz[ks] = *(const bf16x8*)(lsb + brow * 128 +
                            (((ks << 6) + (lg << 4)) ^ ((brow & 7) << 4)));
            }
            const float mj = mj_[st];
            #pragma unroll
            for (int mt = 0; mt < 2; ++mt) {
                const int srow = (w << 5) + (mt << 4) + ln15;
                const bf16x8 ay = *(const bf16x8*)(ysb + srow * 64 +
                        (((st << 5) + ((lg & 1) << 4)) ^ ((srow & 3) << 4)));

                f32x4 acc = {0.f, 0.f, 0.f, 0.f};
                acc = __builtin_amdgcn_mfma_f32_16x16x32_bf16(az[mt][0], bz[0], acc, 0, 0, 0);
                acc = __builtin_amdgcn_mfma_f32_16x16x32_bf16(az[mt][1], bz[1], acc, 0, 0, 0);
                acc = __builtin_amdgcn_mfma_f32_16x16x32_bf16(ay,        by_[st], acc, 0, 0, 0);

                #pragma unroll
                for (int reg = 0; reg < 4; ++reg)
                    vout[st][mt][reg] = acc[reg] + mj;
            }
        }

        // ---- epilogue: transpose through LDS, full-line stores ----
        __syncthreads();                      // all frag reads done
        float* os = (float*)smem;             // 128 x OPAD f32 (reuses zs+ys)
        #pragma unroll
        for (int st = 0; st < 2; ++st) {
            const int col = (st << 4) + ln15;
            #pragma unroll
            for (int mt = 0; mt < 2; ++mt) {
                const int rb = (w << 5) + (mt << 4) + (lg << 2);
                #pragma unroll
                for (int reg = 0; reg < 4; ++reg)
                    os[(rb + reg) * OPAD + col] = vout[st][mt][reg];
            }
        }
        __syncthreads();
        {
            const int c4 = (tid & 7) << 2;    // 0..28
            #pragma unroll
            for (int it = 0; it < 4; ++it) {
                const int row = (it << 5) + (tid >> 3);   // 0..127
                const float* p = os + row * OPAD + c4;
                f32x4 v = { p[0], p[1], p[2], p[3] };
                __builtin_nontemporal_store(v,
                    (f32x4*)&out[(size_t)row * D_TOTAL + D_Z + j0 + c4]);
            }
        }
    } else {
        // ========== z-part: 16 samples x 64 cols via MFMA (R11 verbatim) ==========
        const int s0 = bb * 16;

        const int w    = tid >> 6;
        const int lane = tid & 63;
        const int ln15 = lane & 15;
        const int lg   = lane >> 4;
        const int j = (w << 4) + ln15;     // out col 0..63

        // stage load into regs first
        float4 sz0, sz1;
        const int row = (tid >> 3) & 15;
        const int c8  = (tid & 7) << 3;
        const bool do_stage = (tid < 128);
        if (do_stage) {
            const float* p = eps + (size_t)(s0 + row) * D_TOTAL + c8;
            sz0 = *(const float4*)p;
            sz1 = *(const float4*)(p + 4);
        }

        // B-frags: Lz row j, zero-masked beyond the triangle (k > j)
        const float* lzr = Lz + j * (j + 1) / 2;
        bf16x8 bz[2];
        #pragma unroll
        for (int ks = 0; ks < 2; ++ks) {
            float v[8];
            #pragma unroll
            for (int e = 0; e < 8; ++e) {
                const int k = (ks << 5) + (lg << 3) + e;
                v[e] = (k <= j) ? lzr[k] : 0.0f;
            }
            bz[ks] = packbf(make_float4(v[0], v[1], v[2], v[3]),
                            make_float4(v[4], v[5], v[6], v[7]));
        }

        if (do_stage) {
            *(bf16x8*)(zsb + row * 128 + ((c8 << 1) ^ ((row & 7) << 4))) =
                packbf(sz0, sz1);
        }
        __syncthreads();

        // A-frags: eps_z rows from LDS
        bf16x8 az[2];
        #pragma unroll
        for (int ks = 0; ks < 2; ++ks) {
            az[ks] = *(const bf16x8*)(zsb + ln15 * 128 +
                        (((ks << 6) + (lg << 4)) ^ ((ln15 & 7) << 4)));
        }

        f32x4 acc = {0.f, 0.f, 0.f, 0.f};
        acc = __builtin_amdgcn_mfma_f32_16x16x32_bf16(az[0], bz[0], acc, 0, 0, 0);
        acc = __builtin_amdgcn_mfma_f32_16x16x32_bf16(az[1], bz[1], acc, 0, 0, 0);

        const float mj = m[j];
        #pragma unroll
        for (int reg = 0; reg < 4; ++reg) {
            __builtin_nontemporal_store(acc[reg] + mj,
                &out[(size_t)(s0 + (lg << 2) + reg) * D_TOTAL + j]);
        }
    }
}

extern "C" void kernel_launch(void* const* d_in, const int* in_sizes, int n_in,
                              void* d_out, int out_size, void* d_ws, size_t ws_size,
                              hipStream_t stream) {
    const float* m   = (const float*)d_in[0];
    const float* Lz  = (const float*)d_in[1];
    const float* Ly  = (const float*)d_in[2];
    const float* Lyz = (const float*)d_in[3];
    const float* eps = (const float*)d_in[4];
    float* out = (float*)d_out;

    dim3 grid(N_ZB + N_YB);  // 520
    dim3 block(256);
    hipLaunchKernelGGL(sv_kernel, grid, block, 0, stream,
                       m, Lz, Ly, Lyz, eps, out);
}